// Round 8
// baseline (651.169 us; speedup 1.0000x reference)
//
#include <hip/hip_runtime.h>

#define BATCH 512
#define SEQ   512
#define IN    28
#define HID   128
#define NCLS  10
#define ROWS  2
// h layout (R5-verified): 16 chunks of 8 floats, each padded to 12 floats (48B, 16B-aligned).
// Slice bases at 48B stride -> banks {0,12,24,4,16,28,8,20}x2: worst 2-way alias (free, m136).
#define PADDR(k)  ((((k) >> 3) * 12) + ((k) & 7))
#define HSTRIDE   (16 * 12)   // 192 floats per row

__device__ __forceinline__ float fast_tanh(float x) {
    float e = __expf(2.0f * x);
    return 1.0f - 2.0f * __builtin_amdgcn_rcpf(e + 1.0f);
}

template<int CTRL>
__device__ __forceinline__ float dpp_add(float v) {
    int n = __builtin_amdgcn_update_dpp(0, __float_as_int(v), CTRL, 0xF, 0xF, true);
    return v + __int_as_float(n);
}
// 16-lane reduce; valid in lane sl==0 of each 16-lane row (R5-verified ctrl sequence).
// DPP row_ror:N reads lane (i-N)&15, i.e. pulls from lane (i+16-N)&15.
__device__ __forceinline__ float reduce16(float v) {
    v = dpp_add<0xB1>(v);     // quad_perm xor1
    v = dpp_add<0x4E>(v);     // quad_perm xor2
    v = dpp_add<0x12C>(v);    // row_ror:12 -> lane i += lane (i+4)&15
    v = dpp_add<0x128>(v);    // row_ror:8  -> lane i += lane (i+8)&15
    return v;
}

__global__ __launch_bounds__(1024, 4)
void rnn2_kernel(const float* __restrict__ x,
                 const float* __restrict__ W_ih0, const float* __restrict__ W_hh0,
                 const float* __restrict__ b_ih0, const float* __restrict__ b_hh0,
                 const float* __restrict__ W_ih1, const float* __restrict__ W_hh1,
                 const float* __restrict__ b_ih1, const float* __restrict__ b_hh1,
                 const float* __restrict__ W_fc,  const float* __restrict__ b_fc,
                 float* __restrict__ out)
{
    __shared__ __align__(16) float h0buf[2][ROWS][HSTRIDE];
    __shared__ __align__(16) float h1buf[2][ROWS][HSTRIDE];

    const int t  = threadIdx.x;   // 0..1023
    const int g  = t >> 4;        // unit-group 0..63 -> units 2g, 2g+1
    const int sl = t & 15;        // k-slice 0..15 (8 k each)
    const int j0 = 2 * g;
    const int hk = 8 * sl;

    // ---- weights: 2 units x (2 ih0 + 8 hh0 + 8 ih1 + 8 hh1) = 52 floats/thread
    float wih0[2][2], whh0[2][8], wih1[2][8], whh1[2][8];
    #pragma unroll
    for (int u = 0; u < 2; ++u) {
        #pragma unroll
        for (int kk = 0; kk < 2; ++kk)
            wih0[u][kk] = (sl < 14) ? W_ih0[(j0 + u) * IN + 2 * sl + kk] : 0.0f;
        const float* p0 = W_hh0 + (j0 + u) * HID + hk;
        const float* p1 = W_ih1 + (j0 + u) * HID + hk;
        const float* p2 = W_hh1 + (j0 + u) * HID + hk;
        #pragma unroll
        for (int k = 0; k < 8; ++k) {
            whh0[u][k] = p0[k];
            wih1[u][k] = p1[k];
            whh1[u][k] = p2[k];
        }
    }
    const float bias0_0 = b_ih0[j0] + b_hh0[j0];
    const float bias0_1 = b_ih0[j0 + 1] + b_hh0[j0 + 1];
    const float bias1_0 = b_ih1[j0] + b_hh1[j0];
    const float bias1_1 = b_ih1[j0 + 1] + b_hh1[j0 + 1];

    if (t < HSTRIDE) {
        #pragma unroll
        for (int r = 0; r < ROWS; ++r) {
            h0buf[0][r][t] = 0.0f;
            h1buf[0][r][t] = 0.0f;
        }
    }

    // ---- x: direct global reads (float2 per slice), prefetched one iteration ahead
    const int xk = (sl < 14) ? 2 * sl : 26;   // sl 14,15 have zero weights; clamp in-bounds
    const float* xrow[ROWS];
    float2 xcur[ROWS];
    #pragma unroll
    for (int r = 0; r < ROWS; ++r) {
        xrow[r] = x + ((size_t)(blockIdx.x * ROWS + r) * SEQ) * IN + xk;
        xcur[r] = *(const float2*)(xrow[r]);  // x(0)
    }

    __syncthreads();

    const int ws0 = PADDR(j0);    // j0 even -> j0, j0+1 adjacent in same chunk

    // ---- pipelined time loop (R6-verified): iteration it computes h0(it) AND h1(it-1).
    //   A: h0(it)   = tanh(Wih0·x(it)    + Whh0·h0(it-1) + b0)   [garbage at it=SEQ, unused]
    //   B: h1(it-1) = tanh(Wih1·h0(it-1) + Whh1·h1(it-2) + b1)   [forced 0 at it=0]
    for (int it = 0; it <= SEQ; ++it) {
        const int rd = it & 1, wr = rd ^ 1;
        const int nxtoff = ((it < SEQ - 1) ? (it + 1) : (SEQ - 1)) * IN;

        float redA[ROWS][2], redB[ROWS][2];
        #pragma unroll
        for (int r = 0; r < ROWS; ++r) {
            float2 xn = *(const float2*)(xrow[r] + nxtoff);   // prefetch x(it+1)

            const float4* h0p = (const float4*)&h0buf[rd][r][12 * sl];
            const float4* h1p = (const float4*)&h1buf[rd][r][12 * sl];
            float4 pA = h0p[0], pB = h0p[1];
            float4 qA = h1p[0], qB = h1p[1];

            #pragma unroll
            for (int u = 0; u < 2; ++u) {
                // A-chain: Wih0·x + Whh0·h0_prev  (8 hh k's on 4 accumulators)
                float a0 = wih0[u][0] * xcur[r].x;
                float a1 = wih0[u][1] * xcur[r].y;
                float a2 = 0.0f, a3 = 0.0f;
                a0 = fmaf(whh0[u][0], pA.x, a0); a1 = fmaf(whh0[u][1], pA.y, a1);
                a2 = fmaf(whh0[u][2], pA.z, a2); a3 = fmaf(whh0[u][3], pA.w, a3);
                a0 = fmaf(whh0[u][4], pB.x, a0); a1 = fmaf(whh0[u][5], pB.y, a1);
                a2 = fmaf(whh0[u][6], pB.z, a2); a3 = fmaf(whh0[u][7], pB.w, a3);

                // B-chain: Wih1·h0_prev + Whh1·h1_prev2
                float c0 = wih1[u][0] * pA.x;
                float c1 = wih1[u][1] * pA.y;
                float c2 = wih1[u][2] * pA.z;
                float c3 = wih1[u][3] * pA.w;
                c0 = fmaf(wih1[u][4], pB.x, c0); c1 = fmaf(wih1[u][5], pB.y, c1);
                c2 = fmaf(wih1[u][6], pB.z, c2); c3 = fmaf(wih1[u][7], pB.w, c3);
                c0 = fmaf(whh1[u][0], qA.x, c0); c1 = fmaf(whh1[u][1], qA.y, c1);
                c2 = fmaf(whh1[u][2], qA.z, c2); c3 = fmaf(whh1[u][3], qA.w, c3);
                c0 = fmaf(whh1[u][4], qB.x, c0); c1 = fmaf(whh1[u][5], qB.y, c1);
                c2 = fmaf(whh1[u][6], qB.z, c2); c3 = fmaf(whh1[u][7], qB.w, c3);

                redA[r][u] = reduce16((a0 + a2) + (a1 + a3));
                redB[r][u] = reduce16((c0 + c2) + (c1 + c3));
            }
            xcur[r] = xn;
        }

        if (sl == 0) {
            #pragma unroll
            for (int r = 0; r < ROWS; ++r) {
                float2 hv0;
                hv0.x = fast_tanh(redA[r][0] + bias0_0);
                hv0.y = fast_tanh(redA[r][1] + bias0_1);
                *(float2*)&h0buf[wr][r][ws0] = hv0;
                float2 hv1;
                if (it == 0) {
                    hv1.x = 0.0f; hv1.y = 0.0f;
                } else {
                    hv1.x = fast_tanh(redB[r][0] + bias1_0);
                    hv1.y = fast_tanh(redB[r][1] + bias1_1);
                }
                *(float2*)&h1buf[wr][r][ws0] = hv1;
            }
        }
        __syncthreads();
    }

    // ---- fc epilogue: it=SEQ wrote h1(511) into buffer wr = (SEQ&1)^1 = 1
    if (t < ROWS * NCLS) {
        const int r = t / NCLS, c = t % NCLS;
        float acc = b_fc[c];
        const float* wf = W_fc + c * HID;
        #pragma unroll 4
        for (int k = 0; k < HID; ++k)
            acc = fmaf(wf[k], h1buf[1][r][PADDR(k)], acc);
        out[(blockIdx.x * ROWS + r) * NCLS + c] = acc;
    }
}

extern "C" void kernel_launch(void* const* d_in, const int* in_sizes, int n_in,
                              void* d_out, int out_size, void* d_ws, size_t ws_size,
                              hipStream_t stream) {
    const float* x     = (const float*)d_in[0];
    const float* W_ih0 = (const float*)d_in[1];
    const float* W_hh0 = (const float*)d_in[2];
    const float* b_ih0 = (const float*)d_in[3];
    const float* b_hh0 = (const float*)d_in[4];
    const float* W_ih1 = (const float*)d_in[5];
    const float* W_hh1 = (const float*)d_in[6];
    const float* b_ih1 = (const float*)d_in[7];
    const float* b_hh1 = (const float*)d_in[8];
    const float* W_fc  = (const float*)d_in[9];
    const float* b_fc  = (const float*)d_in[10];
    float* out = (float*)d_out;

    rnn2_kernel<<<dim3(BATCH / ROWS), dim3(1024), 0, stream>>>(
        x, W_ih0, W_hh0, b_ih0, b_hh0, W_ih1, W_hh1, b_ih1, b_hh1, W_fc, b_fc, out);
}